// Round 3
// baseline (337.438 us; speedup 1.0000x reference)
//
#include <hip/hip_runtime.h>
#include <hip/hip_fp16.h>

#define N_NODES   100000
#define N_EDGES   3200000
#define F_IN      256
#define HID       16
#define NCLS      40

#define CHUNK     16384
#define NBLK      ((N_EDGES + CHUNK - 1) / CHUNK)    // 196 edge chunks
#define B2SHIFT   9                                  // 512 nodes per coarse bucket
#define NB2       ((N_NODES + 511) >> B2SHIFT)       // 196 buckets
#define BCAP      17408                              // LDS edge cache in build (mean 16384, +8 sigma)
#define K1_GRID   256
#define NPB       391                                // gemm nodes per block (256*391 >= 100000)

// ---- K1: per-chunk coarse histogram (blocks < NBLK) + full layer-1 GEMM (all blocks) ----
// gemm is dinv-free (y1h = raw x@W1), so it no longer depends on build -> runs first,
// streaming 102.4 MB across the whole chip while the 196 hist blocks hide under it.
__global__ __launch_bounds__(512) void k1_hist_gemm(const int* __restrict__ ei,
                                                    const float* __restrict__ x,
                                                    const float* __restrict__ W1,
                                                    int* __restrict__ hist_blk,
                                                    __half* __restrict__ y1h) {
    __shared__ float W1s[F_IN * HID];    // 16 KB; aliased as int hist during phase A
    int* h = (int*)W1s;
    int blk = blockIdx.x, t = threadIdx.x;

    if (blk < NBLK) {
        for (int i = t; i < NB2; i += 512) h[i] = 0;
        __syncthreads();
        int e0 = blk * CHUNK;
        int eN = min(CHUNK, N_EDGES - e0);           // always %4 == 0
        const int4* d4 = (const int4*)(ei + N_EDGES + e0);
        for (int i = t; i < (eN >> 2); i += 512) {
            int4 d = d4[i];
            atomicAdd(&h[d.x >> B2SHIFT], 1);
            atomicAdd(&h[d.y >> B2SHIFT], 1);
            atomicAdd(&h[d.z >> B2SHIFT], 1);
            atomicAdd(&h[d.w >> B2SHIFT], 1);
        }
        __syncthreads();
        for (int i = t; i < NB2; i += 512) hist_blk[i * NBLK + blk] = h[i];  // bucket-major
        __syncthreads();                              // h dead before W1s overwrite
    }

    // ---- gemm phase: y1h[n,h] = fp16( sum_k x[n,k]*W1[k,h] ) ----
    #pragma unroll
    for (int i = 0; i < (F_IN * HID) / 512; i++) W1s[t + i * 512] = W1[t + i * 512];
    __syncthreads();

    int n = blk * NPB + t;
    if (t >= NPB || n >= N_NODES) return;

    const float4* xr = (const float4*)(x + (size_t)n * F_IN);
    float acc[HID];
    #pragma unroll
    for (int j = 0; j < HID; j++) acc[j] = 0.f;

    #pragma unroll 4
    for (int k4 = 0; k4 < F_IN / 4; k4++) {
        float4 xv = xr[k4];
        int k = k4 * 4;
        #pragma unroll
        for (int hh = 0; hh < HID; hh++) {
            acc[hh] += xv.x * W1s[(k + 0) * HID + hh] + xv.y * W1s[(k + 1) * HID + hh]
                     + xv.z * W1s[(k + 2) * HID + hh] + xv.w * W1s[(k + 3) * HID + hh];
        }
    }
    __half2 hp[8];
    #pragma unroll
    for (int j = 0; j < 8; j++)
        hp[j] = __float22half2_rn(make_float2(acc[2 * j], acc[2 * j + 1]));
    float4* o = (float4*)(y1h + (size_t)n * HID);
    o[0] = ((float4*)hp)[0];
    o[1] = ((float4*)hp)[1];
}

// ---- K2: scatter edges into disjoint sub-ranges; per-bucket prefix recomputed in-block ----
// (rowscan kernel deleted: each block reads the 154 KB L2-resident hist_blk and derives
//  its own cur[] = global bucket base + this block's offset)
// pack: (dst & 511) << 17 | src   (src < 2^17)
__global__ __launch_bounds__(512) void k2_bin(const int* __restrict__ ei,
                                              const int* __restrict__ hist_blk,
                                              int* __restrict__ buf) {
    __shared__ int cur[NB2];
    __shared__ int sc[256];
    int blk = blockIdx.x, t = threadIdx.x;
    int pre = 0, tot = 0;
    if (t < NB2) {
        const int* row = hist_blk + t * NBLK;
        for (int k = 0; k < NBLK; k++) {
            int v = row[k];
            pre += (k < blk) ? v : 0;
            tot += v;
        }
    }
    if (t < 256) sc[t] = tot;
    __syncthreads();
    for (int off = 1; off < 256; off <<= 1) {
        int u = 0;
        if (t < 256 && t >= off) u = sc[t - off];
        __syncthreads();
        if (t < 256) sc[t] += u;
        __syncthreads();
    }
    if (t < NB2) cur[t] = (sc[t] - tot) + pre;       // bucket_base + this block's prefix
    __syncthreads();

    int e0 = blk * CHUNK;
    int eN = min(CHUNK, N_EDGES - e0);               // always %4 == 0
    const int4* s4 = (const int4*)(ei + e0);
    const int4* d4 = (const int4*)(ei + N_EDGES + e0);
    for (int i = t; i < (eN >> 2); i += 512) {
        int4 d = d4[i], s = s4[i];
        int p0 = atomicAdd(&cur[d.x >> B2SHIFT], 1); buf[p0] = ((d.x & 511) << 17) | s.x;
        int p1 = atomicAdd(&cur[d.y >> B2SHIFT], 1); buf[p1] = ((d.y & 511) << 17) | s.y;
        int p2 = atomicAdd(&cur[d.z >> B2SHIFT], 1); buf[p2] = ((d.z & 511) << 17) | s.z;
        int p3 = atomicAdd(&cur[d.w >> B2SHIFT], 1); buf[p3] = ((d.w & 511) << 17) | s.w;
    }
}

// ---- K3: per-bucket fine build -> rowptr, dinv, csr_src (bucket cached in LDS) ----
__global__ __launch_bounds__(512) void k3_build(const int* __restrict__ buf,
                                               const int* __restrict__ hist_blk,
                                               int* __restrict__ rowptr,
                                               float* __restrict__ dinv,
                                               int* __restrict__ csr_src) {
    __shared__ int lbuf[BCAP];
    __shared__ int hist[512], offs[512], cur[512];
    __shared__ int sc[256];
    __shared__ int s_base, s_cnt;
    int b = blockIdx.x, t = threadIdx.x;

    int tot = 0;
    if (t < NB2) {
        const int* row = hist_blk + t * NBLK;
        for (int k = 0; k < NBLK; k++) tot += row[k];
    }
    if (t < 256) sc[t] = tot;
    hist[t] = 0;
    __syncthreads();
    for (int off = 1; off < 256; off <<= 1) {
        int u = 0;
        if (t < 256 && t >= off) u = sc[t - off];
        __syncthreads();
        if (t < 256) sc[t] += u;
        __syncthreads();
    }
    if (t == b) { s_base = sc[b] - tot; s_cnt = tot; }
    __syncthreads();
    int base = s_base, cnt = s_cnt;

    for (int i = t; i < cnt; i += 512) {
        int v = buf[base + i];
        if (i < BCAP) lbuf[i] = v;
        atomicAdd(&hist[v >> 17], 1);
    }
    __syncthreads();
    int v = hist[t];
    offs[t] = v;
    __syncthreads();
    for (int off = 1; off < 512; off <<= 1) {
        int u = (t >= off) ? offs[t - off] : 0;
        __syncthreads();
        offs[t] += u;
        __syncthreads();
    }
    int ex = offs[t] - v;   // exclusive scan
    int n = (b << B2SHIFT) + t;
    if (n < N_NODES) {
        rowptr[n] = base + ex;
        dinv[n]   = rsqrtf((float)(v + 1));  // +1 self-loop
    }
    if (b == 0 && t == 0) rowptr[N_NODES] = N_EDGES;
    cur[t] = ex;
    __syncthreads();
    for (int i = t; i < cnt; i += 512) {
        int p = (i < BCAP) ? lbuf[i] : buf[base + i];
        int pos = atomicAdd(&cur[p >> 17], 1);        // LDS atomic
        csr_src[base + pos] = p & 0x1FFFF;
    }
}

// ---- helper: accumulate one fp16 row scaled by w into acc[16] ----
__device__ __forceinline__ void acc_row_s(const float4* __restrict__ tab, int s, float w, float* acc) {
    float4 v0 = tab[(size_t)s * 2 + 0];
    float4 v1 = tab[(size_t)s * 2 + 1];
    const __half2* a0 = (const __half2*)&v0;
    const __half2* a1 = (const __half2*)&v1;
    #pragma unroll
    for (int j = 0; j < 4; j++) {
        float2 f0 = __half22float2(a0[j]);
        float2 f1 = __half22float2(a1[j]);
        acc[2 * j]         += w * f0.x;
        acc[2 * j + 1]     += w * f0.y;
        acc[8 + 2 * j]     += w * f1.x;
        acc[8 + 2 * j + 1] += w * f1.y;
    }
}

// ---- helper: two scaled fp16 rows with all 4 row-loads in flight ----
__device__ __forceinline__ void acc_row2_s(const float4* __restrict__ tab, int s0, int s1,
                                           float w0, float w1, float* acc) {
    float4 v0 = tab[(size_t)s0 * 2 + 0];
    float4 v1 = tab[(size_t)s0 * 2 + 1];
    float4 v2 = tab[(size_t)s1 * 2 + 0];
    float4 v3 = tab[(size_t)s1 * 2 + 1];
    const __half2* a0 = (const __half2*)&v0;
    const __half2* a1 = (const __half2*)&v1;
    const __half2* b0 = (const __half2*)&v2;
    const __half2* b1 = (const __half2*)&v3;
    #pragma unroll
    for (int j = 0; j < 4; j++) {
        float2 f0 = __half22float2(a0[j]);
        float2 f1 = __half22float2(a1[j]);
        float2 g0 = __half22float2(b0[j]);
        float2 g1 = __half22float2(b1[j]);
        acc[2 * j]         += w0 * f0.x + w1 * g0.x;
        acc[2 * j + 1]     += w0 * f0.y + w1 * g0.y;
        acc[8 + 2 * j]     += w0 * f1.x + w1 * g1.x;
        acc[8 + 2 * j + 1] += w0 * f1.y + w1 * g1.y;
    }
}

// ---- unscaled variants (zh is pre-scaled for layer 2) ----
__device__ __forceinline__ void acc_row(const float4* __restrict__ tab, int s, float* acc) {
    float4 v0 = tab[(size_t)s * 2 + 0];
    float4 v1 = tab[(size_t)s * 2 + 1];
    const __half2* a0 = (const __half2*)&v0;
    const __half2* a1 = (const __half2*)&v1;
    #pragma unroll
    for (int j = 0; j < 4; j++) {
        float2 f0 = __half22float2(a0[j]);
        float2 f1 = __half22float2(a1[j]);
        acc[2 * j]         += f0.x;
        acc[2 * j + 1]     += f0.y;
        acc[8 + 2 * j]     += f1.x;
        acc[8 + 2 * j + 1] += f1.y;
    }
}

__device__ __forceinline__ void acc_row2(const float4* __restrict__ tab, int s0, int s1, float* acc) {
    float4 v0 = tab[(size_t)s0 * 2 + 0];
    float4 v1 = tab[(size_t)s0 * 2 + 1];
    float4 v2 = tab[(size_t)s1 * 2 + 0];
    float4 v3 = tab[(size_t)s1 * 2 + 1];
    const __half2* a0 = (const __half2*)&v0;
    const __half2* a1 = (const __half2*)&v1;
    const __half2* b0 = (const __half2*)&v2;
    const __half2* b1 = (const __half2*)&v3;
    #pragma unroll
    for (int j = 0; j < 4; j++) {
        float2 f0 = __half22float2(a0[j]);
        float2 f1 = __half22float2(a1[j]);
        float2 g0 = __half22float2(b0[j]);
        float2 g1 = __half22float2(b1[j]);
        acc[2 * j]         += f0.x + g0.x;
        acc[2 * j + 1]     += f0.y + g0.y;
        acc[8 + 2 * j]     += f1.x + g1.x;
        acc[8 + 2 * j + 1] += f1.y + g1.y;
    }
}

// ---- gather 1 (4 lanes/node): zh = fp16( dinv_n * relu(dinv_n * sum dinv_s*y_s + b1) ) ----
__global__ __launch_bounds__(256) void gather1_kernel(const int* __restrict__ rowptr,
                                                      const int* __restrict__ csr_src,
                                                      const __half* __restrict__ y1h,
                                                      const float* __restrict__ b1,
                                                      const float* __restrict__ dinv,
                                                      __half* __restrict__ zh) {
    int n   = blockIdx.x * 64 + (threadIdx.x >> 2);
    int sub = threadIdx.x & 3;
    if (n >= N_NODES) return;
    const float4* tab = (const float4*)y1h;
    float dvn = dinv[n];
    int beg = rowptr[n], end = rowptr[n + 1];
    float acc[16];
    #pragma unroll
    for (int i = 0; i < 16; i++) acc[i] = 0.f;
    if (sub == 0) acc_row_s(tab, n, dvn, acc);        // self-loop
    int e = beg + sub;
    for (; e + 4 < end; e += 8) {
        int s0 = csr_src[e], s1 = csr_src[e + 4];
        acc_row2_s(tab, s0, s1, dinv[s0], dinv[s1], acc);
    }
    if (e < end) {
        int s = csr_src[e];
        acc_row_s(tab, s, dinv[s], acc);
    }
    #pragma unroll
    for (int m = 1; m < 4; m <<= 1) {
        #pragma unroll
        for (int i = 0; i < 16; i++) acc[i] += __shfl_xor(acc[i], m, 4);
    }
    if (sub < 2) {
        const float4* b1q = (const float4*)b1;
        float4 ba = b1q[sub * 2], bb = b1q[sub * 2 + 1];
        float bv[8] = {ba.x, ba.y, ba.z, ba.w, bb.x, bb.y, bb.z, bb.w};
        __half2 outp[4];
        #pragma unroll
        for (int j = 0; j < 4; j++) {
            float2 r;
            r.x = fmaxf(dvn * acc[sub * 8 + 2 * j]     + bv[2 * j],     0.f) * dvn;
            r.y = fmaxf(dvn * acc[sub * 8 + 2 * j + 1] + bv[2 * j + 1], 0.f) * dvn;
            outp[j] = __float22half2_rn(r);
        }
        *(float4*)(zh + (size_t)n * HID + sub * 8) = *(float4*)outp;
    }
}

// ---- gather 2 + output GEMM fused: out[n,c] = dinv_n*(agg@W2)[c] + b2[c] ----
__global__ __launch_bounds__(256) void gather2_kernel(const int* __restrict__ rowptr,
                                                      const int* __restrict__ csr_src,
                                                      const __half* __restrict__ zh,
                                                      const float* __restrict__ W2,
                                                      const float* __restrict__ b2,
                                                      const float* __restrict__ dinv,
                                                      float* __restrict__ out) {
    __shared__ float W2s[HID * NCLS];   // 640 floats
    __shared__ float b2s[NCLS];
    int t = threadIdx.x;
    for (int i = t; i < HID * NCLS; i += 256) W2s[i] = W2[i];
    if (t < NCLS) b2s[t] = b2[t];
    __syncthreads();

    int n   = blockIdx.x * 64 + (t >> 2);
    int sub = t & 3;
    if (n >= N_NODES) return;
    const float4* tab = (const float4*)zh;
    int beg = rowptr[n], end = rowptr[n + 1];
    float acc[16];
    #pragma unroll
    for (int i = 0; i < 16; i++) acc[i] = 0.f;
    if (sub == 0) acc_row(tab, n, acc);               // self-loop (zh pre-scaled)
    int e = beg + sub;
    for (; e + 4 < end; e += 8)
        acc_row2(tab, csr_src[e], csr_src[e + 4], acc);
    if (e < end) acc_row(tab, csr_src[e], acc);
    #pragma unroll
    for (int m = 1; m < 4; m <<= 1) {
        #pragma unroll
        for (int i = 0; i < 16; i++) acc[i] += __shfl_xor(acc[i], m, 4);
    }
    // each lane computes 10 contiguous classes
    float dv = dinv[n];
    int c0 = sub * 10;
    float o[10];
    #pragma unroll
    for (int j = 0; j < 10; j++) o[j] = 0.f;
    #pragma unroll
    for (int h = 0; h < HID; h++) {
        float a = acc[h];
        const float* w = &W2s[h * NCLS + c0];
        #pragma unroll
        for (int j = 0; j < 10; j++) o[j] += a * w[j];
    }
    float* op = out + (size_t)n * NCLS + c0;
    #pragma unroll
    for (int j = 0; j < 5; j++) {
        float2 r = make_float2(dv * o[2 * j]     + b2s[c0 + 2 * j],
                               dv * o[2 * j + 1] + b2s[c0 + 2 * j + 1]);
        *(float2*)(op + 2 * j) = r;
    }
}

extern "C" void kernel_launch(void* const* d_in, const int* in_sizes, int n_in,
                              void* d_out, int out_size, void* d_ws, size_t ws_size,
                              hipStream_t stream) {
    const float* x   = (const float*)d_in[0];
    const int*   ei  = (const int*)  d_in[1];   // [2, E] int32
    const float* W1  = (const float*)d_in[2];
    const float* b1  = (const float*)d_in[3];
    const float* W2  = (const float*)d_in[4];
    const float* b2  = (const float*)d_in[5];
    float* out = (float*)d_out;

    char* ws = (char*)d_ws;
    size_t off = 0;
    int*   hist_blk = (int*)(ws + off); off += (size_t)NB2 * NBLK * 4;       // 154 KB
    off = (off + 15) & ~(size_t)15;
    int*    rowptr  = (int*)   (ws + off); off += (size_t)(N_NODES + 1) * 4;
    off = (off + 15) & ~(size_t)15;
    float*  dinv    = (float*) (ws + off); off += (size_t)N_NODES * 4;
    int*    csr_src = (int*)   (ws + off); off += (size_t)N_EDGES * 4;          // 12.8 MB
    int*    buf     = (int*)   (ws + off); off += (size_t)N_EDGES * 4;          // 12.8 MB
    __half* y1h     = (__half*)(ws + off); off += (size_t)N_NODES * HID * 2;    //  3.2 MB
    __half* zh      = (__half*)(ws + off); off += (size_t)N_NODES * HID * 2;    //  3.2 MB

    k1_hist_gemm <<<K1_GRID, 512, 0, stream>>>(ei, x, W1, hist_blk, y1h);
    k2_bin       <<<NBLK, 512, 0, stream>>>(ei, hist_blk, buf);
    k3_build     <<<NB2, 512, 0, stream>>>(buf, hist_blk, rowptr, dinv, csr_src);
    gather1_kernel<<<(N_NODES + 63) / 64, 256, 0, stream>>>(rowptr, csr_src, y1h, b1, dinv, zh);
    gather2_kernel<<<(N_NODES + 63) / 64, 256, 0, stream>>>(rowptr, csr_src, zh, W2, b2, dinv, out);
}

// Round 4
// 325.241 us; speedup vs baseline: 1.0375x; 1.0375x over previous
//
#include <hip/hip_runtime.h>
#include <hip/hip_fp16.h>

#define N_NODES   100000
#define N_EDGES   3200000
#define F_IN      256
#define HID       16
#define NCLS      40

#define CHUNK     16384
#define NBLK      ((N_EDGES + CHUNK - 1) / CHUNK)    // 196 edge chunks
#define B2SHIFT   9                                  // 512 nodes per coarse bucket
#define NB2       ((N_NODES + 511) >> B2SHIFT)       // 196 buckets
#define BCAP      17408                              // LDS edge cache in build (mean 16384, +8 sigma)

// ---- K1: per-chunk coarse histogram + layer-1 GEMM (2 nodes/thread, reg-blocked) ----
// grid == NBLK == 196: every block does one hist chunk, then 512 gemm nodes.
// y1h = raw fp16(x@W1); dinv scaling applied later in k3 (when dinv exists).
__global__ __launch_bounds__(256) void k1_hist_gemm(const int* __restrict__ ei,
                                                    const float* __restrict__ x,
                                                    const float* __restrict__ W1,
                                                    int* __restrict__ hist_blk,
                                                    __half* __restrict__ y1h) {
    __shared__ float W1s[F_IN * HID];    // 16 KB; aliased as int hist during phase A
    int* h = (int*)W1s;
    int blk = blockIdx.x, t = threadIdx.x;

    // ---- hist phase ----
    for (int i = t; i < NB2; i += 256) h[i] = 0;
    __syncthreads();
    int e0 = blk * CHUNK;
    int eN = min(CHUNK, N_EDGES - e0);               // always %4 == 0
    const int4* d4 = (const int4*)(ei + N_EDGES + e0);
    for (int i = t; i < (eN >> 2); i += 256) {
        int4 d = d4[i];
        atomicAdd(&h[d.x >> B2SHIFT], 1);
        atomicAdd(&h[d.y >> B2SHIFT], 1);
        atomicAdd(&h[d.z >> B2SHIFT], 1);
        atomicAdd(&h[d.w >> B2SHIFT], 1);
    }
    __syncthreads();
    for (int i = t; i < NB2; i += 256) hist_blk[i * NBLK + blk] = h[i];  // bucket-major
    __syncthreads();                                  // h dead before W1s overwrite

    // ---- gemm phase: 2 nodes/thread (halves per-node LDS weight reads) ----
    #pragma unroll
    for (int i = 0; i < (F_IN * HID) / 256; i++) W1s[t + i * 256] = W1[t + i * 256];
    __syncthreads();

    int n0 = blk * 512 + t;
    int n1 = n0 + 256;
    if (n0 >= N_NODES) return;
    bool v1 = (n1 < N_NODES);

    const float4* xr0 = (const float4*)(x + (size_t)n0 * F_IN);
    const float4* xr1 = (const float4*)(x + (size_t)(v1 ? n1 : n0) * F_IN);  // safe dummy
    float acc0[HID], acc1[HID];
    #pragma unroll
    for (int j = 0; j < HID; j++) { acc0[j] = 0.f; acc1[j] = 0.f; }

    #pragma unroll 2
    for (int k4 = 0; k4 < F_IN / 4; k4++) {
        float4 xa = xr0[k4];
        float4 xb = xr1[k4];
        int k = k4 * 4;
        #pragma unroll
        for (int hh = 0; hh < HID; hh++) {
            float w0 = W1s[(k + 0) * HID + hh];
            float w1 = W1s[(k + 1) * HID + hh];
            float w2 = W1s[(k + 2) * HID + hh];
            float w3 = W1s[(k + 3) * HID + hh];
            acc0[hh] += xa.x * w0 + xa.y * w1 + xa.z * w2 + xa.w * w3;
            acc1[hh] += xb.x * w0 + xb.y * w1 + xb.z * w2 + xb.w * w3;
        }
    }
    {
        __half2 hp[8];
        #pragma unroll
        for (int j = 0; j < 8; j++)
            hp[j] = __float22half2_rn(make_float2(acc0[2 * j], acc0[2 * j + 1]));
        float4* o = (float4*)(y1h + (size_t)n0 * HID);
        o[0] = ((float4*)hp)[0];
        o[1] = ((float4*)hp)[1];
    }
    if (v1) {
        __half2 hp[8];
        #pragma unroll
        for (int j = 0; j < 8; j++)
            hp[j] = __float22half2_rn(make_float2(acc1[2 * j], acc1[2 * j + 1]));
        float4* o = (float4*)(y1h + (size_t)n1 * HID);
        o[0] = ((float4*)hp)[0];
        o[1] = ((float4*)hp)[1];
    }
}

// ---- K2: scatter edges into disjoint sub-ranges; per-bucket prefix recomputed in-block ----
// pack: (dst & 511) << 17 | src   (src < 2^17)
__global__ __launch_bounds__(512) void k2_bin(const int* __restrict__ ei,
                                              const int* __restrict__ hist_blk,
                                              int* __restrict__ buf) {
    __shared__ int cur[NB2];
    __shared__ int sc[256];
    int blk = blockIdx.x, t = threadIdx.x;
    int pre = 0, tot = 0;
    if (t < NB2) {
        const int* row = hist_blk + t * NBLK;
        for (int k = 0; k < NBLK; k++) {
            int v = row[k];
            pre += (k < blk) ? v : 0;
            tot += v;
        }
    }
    if (t < 256) sc[t] = tot;
    __syncthreads();
    for (int off = 1; off < 256; off <<= 1) {
        int u = 0;
        if (t < 256 && t >= off) u = sc[t - off];
        __syncthreads();
        if (t < 256) sc[t] += u;
        __syncthreads();
    }
    if (t < NB2) cur[t] = (sc[t] - tot) + pre;       // bucket_base + this block's prefix
    __syncthreads();

    int e0 = blk * CHUNK;
    int eN = min(CHUNK, N_EDGES - e0);               // always %4 == 0
    const int4* s4 = (const int4*)(ei + e0);
    const int4* d4 = (const int4*)(ei + N_EDGES + e0);
    for (int i = t; i < (eN >> 2); i += 512) {
        int4 d = d4[i], s = s4[i];
        int p0 = atomicAdd(&cur[d.x >> B2SHIFT], 1); buf[p0] = ((d.x & 511) << 17) | s.x;
        int p1 = atomicAdd(&cur[d.y >> B2SHIFT], 1); buf[p1] = ((d.y & 511) << 17) | s.y;
        int p2 = atomicAdd(&cur[d.z >> B2SHIFT], 1); buf[p2] = ((d.z & 511) << 17) | s.z;
        int p3 = atomicAdd(&cur[d.w >> B2SHIFT], 1); buf[p3] = ((d.w & 511) << 17) | s.w;
    }
}

// ---- K3: per-bucket fine build -> rowptr, dinv, csr_src; ALSO scales y1h row by dinv ----
// (fusing the y1h *= dinv[n] rescale here removes gather1's 6.4M random dinv[src] loads)
__global__ __launch_bounds__(512) void k3_build(const int* __restrict__ buf,
                                               const int* __restrict__ hist_blk,
                                               int* __restrict__ rowptr,
                                               float* __restrict__ dinv,
                                               int* __restrict__ csr_src,
                                               __half* __restrict__ y1h) {
    __shared__ int lbuf[BCAP];
    __shared__ int hist[512], offs[512], cur[512];
    __shared__ int sc[256];
    __shared__ int s_base, s_cnt;
    int b = blockIdx.x, t = threadIdx.x;

    int tot = 0;
    if (t < NB2) {
        const int* row = hist_blk + t * NBLK;
        for (int k = 0; k < NBLK; k++) tot += row[k];
    }
    if (t < 256) sc[t] = tot;
    hist[t] = 0;
    __syncthreads();
    for (int off = 1; off < 256; off <<= 1) {
        int u = 0;
        if (t < 256 && t >= off) u = sc[t - off];
        __syncthreads();
        if (t < 256) sc[t] += u;
        __syncthreads();
    }
    if (t == b) { s_base = sc[b] - tot; s_cnt = tot; }
    __syncthreads();
    int base = s_base, cnt = s_cnt;

    for (int i = t; i < cnt; i += 512) {
        int v = buf[base + i];
        if (i < BCAP) lbuf[i] = v;
        atomicAdd(&hist[v >> 17], 1);
    }
    __syncthreads();
    int v = hist[t];
    offs[t] = v;
    __syncthreads();
    for (int off = 1; off < 512; off <<= 1) {
        int u = (t >= off) ? offs[t - off] : 0;
        __syncthreads();
        offs[t] += u;
        __syncthreads();
    }
    int ex = offs[t] - v;   // exclusive scan
    int n = (b << B2SHIFT) + t;
    if (n < N_NODES) {
        rowptr[n] = base + ex;
        float dv = rsqrtf((float)(v + 1));  // +1 self-loop
        dinv[n] = dv;
        // in-place rescale of this node's y1h row (row owned exclusively by this thread)
        float4* yr = (float4*)(y1h + (size_t)n * HID);
        float4 a = yr[0], bqq = yr[1];
        __half2* ah = (__half2*)&a;
        __half2* bh = (__half2*)&bqq;
        #pragma unroll
        for (int j = 0; j < 4; j++) {
            float2 fa = __half22float2(ah[j]);
            float2 fb = __half22float2(bh[j]);
            ah[j] = __float22half2_rn(make_float2(fa.x * dv, fa.y * dv));
            bh[j] = __float22half2_rn(make_float2(fb.x * dv, fb.y * dv));
        }
        yr[0] = a;
        yr[1] = bqq;
    }
    if (b == 0 && t == 0) rowptr[N_NODES] = N_EDGES;
    cur[t] = ex;
    __syncthreads();
    for (int i = t; i < cnt; i += 512) {
        int p = (i < BCAP) ? lbuf[i] : buf[base + i];
        int pos = atomicAdd(&cur[p >> 17], 1);        // LDS atomic
        csr_src[base + pos] = p & 0x1FFFF;
    }
}

// ---- helper: accumulate one fp16 row (16 halfs as 2 float4) into acc[16] ----
__device__ __forceinline__ void acc_row(const float4* __restrict__ tab, int s, float* acc) {
    float4 v0 = tab[(size_t)s * 2 + 0];
    float4 v1 = tab[(size_t)s * 2 + 1];
    const __half2* a0 = (const __half2*)&v0;
    const __half2* a1 = (const __half2*)&v1;
    #pragma unroll
    for (int j = 0; j < 4; j++) {
        float2 f0 = __half22float2(a0[j]);
        float2 f1 = __half22float2(a1[j]);
        acc[2 * j]         += f0.x;
        acc[2 * j + 1]     += f0.y;
        acc[8 + 2 * j]     += f1.x;
        acc[8 + 2 * j + 1] += f1.y;
    }
}

// ---- helper: two fp16 rows with all 4 row-loads in flight ----
__device__ __forceinline__ void acc_row2(const float4* __restrict__ tab, int s0, int s1, float* acc) {
    float4 v0 = tab[(size_t)s0 * 2 + 0];
    float4 v1 = tab[(size_t)s0 * 2 + 1];
    float4 v2 = tab[(size_t)s1 * 2 + 0];
    float4 v3 = tab[(size_t)s1 * 2 + 1];
    const __half2* a0 = (const __half2*)&v0;
    const __half2* a1 = (const __half2*)&v1;
    const __half2* b0 = (const __half2*)&v2;
    const __half2* b1 = (const __half2*)&v3;
    #pragma unroll
    for (int j = 0; j < 4; j++) {
        float2 f0 = __half22float2(a0[j]);
        float2 f1 = __half22float2(a1[j]);
        float2 g0 = __half22float2(b0[j]);
        float2 g1 = __half22float2(b1[j]);
        acc[2 * j]         += f0.x + g0.x;
        acc[2 * j + 1]     += f0.y + g0.y;
        acc[8 + 2 * j]     += f1.x + g1.x;
        acc[8 + 2 * j + 1] += f1.y + g1.y;
    }
}

// ---- gather 1 (4 lanes/node): zh = fp16( dinv_n * relu(dinv_n * agg + b1) ) ----
// y1h rows are pre-scaled by dinv[src] (done in k3), so the edge loop is pure row-sums.
__global__ __launch_bounds__(256) void gather1_kernel(const int* __restrict__ rowptr,
                                                      const int* __restrict__ csr_src,
                                                      const __half* __restrict__ y1h,
                                                      const float* __restrict__ b1,
                                                      const float* __restrict__ dinv,
                                                      __half* __restrict__ zh) {
    int n   = blockIdx.x * 64 + (threadIdx.x >> 2);
    int sub = threadIdx.x & 3;
    if (n >= N_NODES) return;
    const float4* tab = (const float4*)y1h;
    int beg = rowptr[n], end = rowptr[n + 1];
    float acc[16];
    #pragma unroll
    for (int i = 0; i < 16; i++) acc[i] = 0.f;
    if (sub == 0) acc_row(tab, n, acc);               // self-loop (row pre-scaled by dinv_n)
    int e = beg + sub;
    for (; e + 4 < end; e += 8)
        acc_row2(tab, csr_src[e], csr_src[e + 4], acc);
    if (e < end) acc_row(tab, csr_src[e], acc);
    #pragma unroll
    for (int m = 1; m < 4; m <<= 1) {
        #pragma unroll
        for (int i = 0; i < 16; i++) acc[i] += __shfl_xor(acc[i], m, 4);
    }
    if (sub < 2) {
        float dvn = dinv[n];
        const float4* b1q = (const float4*)b1;
        float4 ba = b1q[sub * 2], bb = b1q[sub * 2 + 1];
        float bv[8] = {ba.x, ba.y, ba.z, ba.w, bb.x, bb.y, bb.z, bb.w};
        __half2 outp[4];
        #pragma unroll
        for (int j = 0; j < 4; j++) {
            float2 r;
            r.x = fmaxf(dvn * acc[sub * 8 + 2 * j]     + bv[2 * j],     0.f) * dvn;
            r.y = fmaxf(dvn * acc[sub * 8 + 2 * j + 1] + bv[2 * j + 1], 0.f) * dvn;
            outp[j] = __float22half2_rn(r);
        }
        *(float4*)(zh + (size_t)n * HID + sub * 8) = *(float4*)outp;
    }
}

// ---- gather 2 + output GEMM fused: out[n,c] = dinv_n*(agg@W2)[c] + b2[c] ----
__global__ __launch_bounds__(256) void gather2_kernel(const int* __restrict__ rowptr,
                                                      const int* __restrict__ csr_src,
                                                      const __half* __restrict__ zh,
                                                      const float* __restrict__ W2,
                                                      const float* __restrict__ b2,
                                                      const float* __restrict__ dinv,
                                                      float* __restrict__ out) {
    __shared__ float W2s[HID * NCLS];   // 640 floats
    __shared__ float b2s[NCLS];
    int t = threadIdx.x;
    for (int i = t; i < HID * NCLS; i += 256) W2s[i] = W2[i];
    if (t < NCLS) b2s[t] = b2[t];
    __syncthreads();

    int n   = blockIdx.x * 64 + (t >> 2);
    int sub = t & 3;
    if (n >= N_NODES) return;
    const float4* tab = (const float4*)zh;
    int beg = rowptr[n], end = rowptr[n + 1];
    float acc[16];
    #pragma unroll
    for (int i = 0; i < 16; i++) acc[i] = 0.f;
    if (sub == 0) acc_row(tab, n, acc);               // self-loop (zh pre-scaled)
    int e = beg + sub;
    for (; e + 4 < end; e += 8)
        acc_row2(tab, csr_src[e], csr_src[e + 4], acc);
    if (e < end) acc_row(tab, csr_src[e], acc);
    #pragma unroll
    for (int m = 1; m < 4; m <<= 1) {
        #pragma unroll
        for (int i = 0; i < 16; i++) acc[i] += __shfl_xor(acc[i], m, 4);
    }
    // each lane computes 10 contiguous classes
    float dv = dinv[n];
    int c0 = sub * 10;
    float o[10];
    #pragma unroll
    for (int j = 0; j < 10; j++) o[j] = 0.f;
    #pragma unroll
    for (int h = 0; h < HID; h++) {
        float a = acc[h];
        const float* w = &W2s[h * NCLS + c0];
        #pragma unroll
        for (int j = 0; j < 10; j++) o[j] += a * w[j];
    }
    float* op = out + (size_t)n * NCLS + c0;
    #pragma unroll
    for (int j = 0; j < 5; j++) {
        float2 r = make_float2(dv * o[2 * j]     + b2s[c0 + 2 * j],
                               dv * o[2 * j + 1] + b2s[c0 + 2 * j + 1]);
        *(float2*)(op + 2 * j) = r;
    }
}

extern "C" void kernel_launch(void* const* d_in, const int* in_sizes, int n_in,
                              void* d_out, int out_size, void* d_ws, size_t ws_size,
                              hipStream_t stream) {
    const float* x   = (const float*)d_in[0];
    const int*   ei  = (const int*)  d_in[1];   // [2, E] int32
    const float* W1  = (const float*)d_in[2];
    const float* b1  = (const float*)d_in[3];
    const float* W2  = (const float*)d_in[4];
    const float* b2  = (const float*)d_in[5];
    float* out = (float*)d_out;

    char* ws = (char*)d_ws;
    size_t off = 0;
    int*   hist_blk = (int*)(ws + off); off += (size_t)NB2 * NBLK * 4;       // 154 KB
    off = (off + 15) & ~(size_t)15;
    int*    rowptr  = (int*)   (ws + off); off += (size_t)(N_NODES + 1) * 4;
    off = (off + 15) & ~(size_t)15;
    float*  dinv    = (float*) (ws + off); off += (size_t)N_NODES * 4;
    int*    csr_src = (int*)   (ws + off); off += (size_t)N_EDGES * 4;          // 12.8 MB
    int*    buf     = (int*)   (ws + off); off += (size_t)N_EDGES * 4;          // 12.8 MB
    __half* y1h     = (__half*)(ws + off); off += (size_t)N_NODES * HID * 2;    //  3.2 MB
    __half* zh      = (__half*)(ws + off); off += (size_t)N_NODES * HID * 2;    //  3.2 MB

    k1_hist_gemm <<<NBLK, 256, 0, stream>>>(ei, x, W1, hist_blk, y1h);
    k2_bin       <<<NBLK, 512, 0, stream>>>(ei, hist_blk, buf);
    k3_build     <<<NB2, 512, 0, stream>>>(buf, hist_blk, rowptr, dinv, csr_src, y1h);
    gather1_kernel<<<(N_NODES + 63) / 64, 256, 0, stream>>>(rowptr, csr_src, y1h, b1, dinv, zh);
    gather2_kernel<<<(N_NODES + 63) / 64, 256, 0, stream>>>(rowptr, csr_src, zh, W2, b2, dinv, out);
}